// Round 11
// baseline (56.133 us; speedup 1.0000x reference)
//
#include <hip/hip_runtime.h>

#define BSES 64
#define EDIM 128
#define HDIM 128
#define KSCALE 2.8853900817779268f  // 2*log2(e): exp(2x) = exp2(KSCALE*x)

__device__ __forceinline__ float fexp2(float x) {
#if __has_builtin(__builtin_amdgcn_exp2f)
  return __builtin_amdgcn_exp2f(x);
#else
  return exp2f(x);
#endif
}
__device__ __forceinline__ float frcp(float x) {
#if __has_builtin(__builtin_amdgcn_rcpf)
  return __builtin_amdgcn_rcpf(x);
#else
  return 1.0f / x;
#endif
}

// 4-way batched reciprocal sum: w0/x0 + w1/x1 + w2/x2 + w3/x3,
// x_j = fma(s_j, v_j, 1). 13 VALU + 1 rcp per 4 elements. (Proven R3+.)
__device__ __forceinline__ float g4(float s0, float s1, float s2, float s3,
                                    float w0, float w1, float w2, float w3,
                                    float4 v, float acc) {
  float x0 = fmaf(s0, v.x, 1.f);
  float x1 = fmaf(s1, v.y, 1.f);
  float x2 = fmaf(s2, v.z, 1.f);
  float x3 = fmaf(s3, v.w, 1.f);
  float p01 = x0 * x1, p23 = x2 * x3;
  float n01 = fmaf(w1, x0, w0 * x1);
  float n23 = fmaf(w3, x2, w2 * x3);
  float num = fmaf(n23, p01, n01 * p23);
  return fmaf(num, frcp(p01 * p23), acc);
}

// Fused projections (UNCHANGED from R10). Blocks [0,nbTP): etp[n][h] natural
// layout. Blocks [nbTP,..): esp4 PACKED [h/4][b][4]; plus C = sum(W3)+b3.
__global__ __launch_bounds__(256) void taa_k1(
    const float* __restrict__ sess, const float* __restrict__ W1,
    const float* __restrict__ b1, const float* __restrict__ emb,
    const float* __restrict__ W2, const float* __restrict__ b2,
    const float* __restrict__ W3, const float* __restrict__ b3,
    float* __restrict__ etp, float* __restrict__ esp4,
    float* __restrict__ C_out, int N, int nbTP) {
  if ((int)blockIdx.x < nbTP) {
    __shared__ float sm[32][132];  // emb tile, padded stride
    const int nb = blockIdx.x * 32;
    for (int k = threadIdx.x; k < 32 * 32; k += 256) {
      int r = k >> 5, c4 = k & 31;
      float4 v = make_float4(0.f, 0.f, 0.f, 0.f);
      if (nb + r < N) v = ((const float4*)(emb + (size_t)(nb + r) * EDIM))[c4];
      *(float4*)&sm[r][c4 * 4] = v;
    }
    __syncthreads();
    const int h4 = (threadIdx.x & 31) * 4;
    const int rg = threadIdx.x >> 5;  // 8 groups of 4 rows
    float acc[4][4];
#pragma unroll
    for (int j = 0; j < 4; ++j)
#pragma unroll
      for (int q = 0; q < 4; ++q) acc[j][q] = 0.f;
    for (int e = 0; e < EDIM; e += 4) {
      float4 w[4];
#pragma unroll
      for (int q = 0; q < 4; ++q)
        w[q] = *(const float4*)(W2 + (size_t)(e + q) * HDIM + h4);
#pragma unroll
      for (int j = 0; j < 4; ++j) {
        float4 em = *(const float4*)&sm[rg * 4 + j][e];
        acc[j][0] = fmaf(em.x, w[0].x, acc[j][0]);
        acc[j][1] = fmaf(em.x, w[0].y, acc[j][1]);
        acc[j][2] = fmaf(em.x, w[0].z, acc[j][2]);
        acc[j][3] = fmaf(em.x, w[0].w, acc[j][3]);
        acc[j][0] = fmaf(em.y, w[1].x, acc[j][0]);
        acc[j][1] = fmaf(em.y, w[1].y, acc[j][1]);
        acc[j][2] = fmaf(em.y, w[1].z, acc[j][2]);
        acc[j][3] = fmaf(em.y, w[1].w, acc[j][3]);
        acc[j][0] = fmaf(em.z, w[2].x, acc[j][0]);
        acc[j][1] = fmaf(em.z, w[2].y, acc[j][1]);
        acc[j][2] = fmaf(em.z, w[2].z, acc[j][2]);
        acc[j][3] = fmaf(em.z, w[2].w, acc[j][3]);
        acc[j][0] = fmaf(em.w, w[3].x, acc[j][0]);
        acc[j][1] = fmaf(em.w, w[3].y, acc[j][1]);
        acc[j][2] = fmaf(em.w, w[3].z, acc[j][2]);
        acc[j][3] = fmaf(em.w, w[3].w, acc[j][3]);
      }
    }
    float4 bb2 = *(const float4*)(b2 + h4);
#pragma unroll
    for (int j = 0; j < 4; ++j) {
      int n = nb + rg * 4 + j;
      if (n < N) {
        float4 o;
        o.x = fexp2((acc[j][0] + bb2.x) * KSCALE);
        o.y = fexp2((acc[j][1] + bb2.y) * KSCALE);
        o.z = fexp2((acc[j][2] + bb2.z) * KSCALE);
        o.w = fexp2((acc[j][3] + bb2.w) * KSCALE);
        *(float4*)(etp + (size_t)n * HDIM + h4) = o;
      }
    }
  } else {
    int t = ((int)blockIdx.x - nbTP) * 256 + threadIdx.x;
    if (t < BSES * HDIM) {
      int b = t >> 7, h = t & 127;
      const float* srow = sess + b * EDIM;
      float acc = 0.f;
#pragma unroll 4
      for (int e = 0; e < EDIM; ++e)
        acc = fmaf(srow[e], W1[e * HDIM + h], acc);
      esp4[(h >> 2) * 256 + b * 4 + (h & 3)] = fexp2((acc + b1[h]) * KSCALE);
    }
    if (t == 0) {
      float s = b3[0];
      for (int i = 0; i < HDIM; ++i) s += W3[i];
      *C_out = s;
    }
  }
}

// ---- k2 helper macros (all static indexing; named buffers) ----
// Load one 16-h chunk of the two target rows (8 coalesced... wave-uniform
// broadcast dwordx4 loads from the STREAMING etp -> this is the prefetched
// operand now).
#define LOADTV(T0, T1, c)                                                   \
  _Pragma("unroll") for (int k_ = 0; k_ < 4; ++k_) {                        \
    T0[k_] = ((const float4*)(tr0 + (c) * 16))[k_];                         \
    T1[k_] = ((const float4*)(tr1 + (c) * 16))[k_];                         \
  }
// Load one 16-h chunk of per-lane session values (4 coalesced dwordx4,
// L1-hot 32 KB array).
#define LOADSP(SS, c)                                                       \
  _Pragma("unroll") for (int k_ = 0; k_ < 4; ++k_)                          \
    SS[k_] = *(const float4*)(esp4 + ((((c) << 2) + k_) << 8) + (lane << 2));
// Score one 16-h chunk: 8 g4 (2 targets x 4 quads); w3 uniform -> s_load.
#define SCORE(T0, T1, SS, c)                                                \
  {                                                                         \
    float w_[16];                                                           \
    _Pragma("unroll") for (int k_ = 0; k_ < 16; ++k_)                       \
      w_[k_] = w3[((c) << 4) + k_];                                         \
    _Pragma("unroll") for (int k_ = 0; k_ < 4; ++k_) {                      \
      acc0 = g4(SS[k_].x, SS[k_].y, SS[k_].z, SS[k_].w, w_[4 * k_],         \
                w_[4 * k_ + 1], w_[4 * k_ + 2], w_[4 * k_ + 3], T0[k_],     \
                acc0);                                                      \
      acc1 = g4(SS[k_].x, SS[k_].y, SS[k_].z, SS[k_].w, w_[4 * k_],         \
                w_[4 * k_ + 1], w_[4 * k_ + 2], w_[4 * k_ + 3], T1[k_],     \
                acc1);                                                      \
    }                                                                       \
  }

// Scoring: lane = session; wave -> 2 targets; tv (streaming etp) DOUBLE-
// BUFFERED so chunk c+1's 8 dwordx4 are in flight during chunk c's 8 g4
// (~272 cy) -- hides the remote-L2/HBM latency that R3-R10 left exposed.
// score[b][n] = C - 2 * sum_h w3[h] * rcp(fma(esp[b][h], etp[n][h], 1))
__global__ __launch_bounds__(256) void taa_k2(
    const float* __restrict__ etp, const float* __restrict__ esp4,
    const float* __restrict__ w3, const float* __restrict__ Cptr,
    float* __restrict__ out, int N) {
  const int lane = threadIdx.x & 63;
  const int wave = blockIdx.x * 4 + (threadIdx.x >> 6);
  const int n0 = wave * 2;
  if (n0 >= N) return;
  const float* tr0 = etp + (size_t)n0 * HDIM;
  const float* tr1 = tr0 + ((n0 + 1 < N) ? HDIM : 0);  // safe dup for tail
  float acc0 = 0.f, acc1 = 0.f;
  float4 tA0[4], tA1[4], tB0[4], tB1[4], spA[4], spB[4];
  LOADTV(tA0, tA1, 0)
  LOADSP(spA, 0)
#pragma unroll 1
  for (int c = 0; c < 8; c += 2) {
    LOADTV(tB0, tB1, c + 1)   // prefetch next chunk (streaming operand)
    LOADSP(spB, c + 1)
    SCORE(tA0, tA1, spA, c)   // compute current (covers prefetch latency)
    if (c + 2 < 8) {
      LOADTV(tA0, tA1, c + 2)
      LOADSP(spA, c + 2)
    }
    SCORE(tB0, tB1, spB, c + 1)
  }
  const float Cv = *Cptr;  // uniform -> s_load
  const float r0 = fmaf(-2.f, acc0, Cv);
  const float r1 = fmaf(-2.f, acc1, Cv);
  float* po = out + (size_t)lane * N + n0;
  if (n0 + 1 < N) {
    float2 r;
    r.x = r0;
    r.y = r1;
    *(float2*)po = r;
  } else {
    *po = r0;
  }
}

extern "C" void kernel_launch(void* const* d_in, const int* in_sizes, int n_in,
                              void* d_out, int out_size, void* d_ws, size_t ws_size,
                              hipStream_t stream) {
  const float* sess = (const float*)d_in[0];
  const float* emb  = (const float*)d_in[1];
  const float* W1   = (const float*)d_in[2];
  const float* b1   = (const float*)d_in[3];
  const float* W2   = (const float*)d_in[4];
  const float* b2   = (const float*)d_in[5];
  const float* W3   = (const float*)d_in[6];
  const float* b3   = (const float*)d_in[7];
  float* out = (float*)d_out;
  const int B = in_sizes[0] / EDIM;   // 64
  const int N = in_sizes[1] / EDIM;   // 20000

  float* etp  = (float*)d_ws;                     // N*128 floats
  float* esp4 = etp + (size_t)N * HDIM;           // B*128 floats (packed)
  float* Cp   = esp4 + (size_t)BSES * HDIM;       // 1 float

  const int nbTP = (N + 31) / 32;                 // 625
  const int nbSP = (B * HDIM + 255) / 256;        // 32
  taa_k1<<<nbTP + nbSP, 256, 0, stream>>>(sess, W1, b1, emb, W2, b2, W3, b3,
                                          etp, esp4, Cp, N, nbTP);
  const int waves = (N + 1) / 2;                  // 2 targets per wave
  taa_k2<<<(waves + 3) / 4, 256, 0, stream>>>(etp, esp4, W3, Cp, out, N);
}

// Round 12
// 43.097 us; speedup vs baseline: 1.3025x; 1.3025x over previous
//
#include <hip/hip_runtime.h>

#define BSES 64
#define EDIM 128
#define HDIM 128
#define KSCALE 2.8853900817779268f  // 2*log2(e): exp(2x) = exp2(KSCALE*x)

__device__ __forceinline__ float fexp2(float x) {
#if __has_builtin(__builtin_amdgcn_exp2f)
  return __builtin_amdgcn_exp2f(x);
#else
  return exp2f(x);
#endif
}
__device__ __forceinline__ float frcp(float x) {
#if __has_builtin(__builtin_amdgcn_rcpf)
  return __builtin_amdgcn_rcpf(x);
#else
  return 1.0f / x;
#endif
}

// 4-way batched reciprocal sum: w0/x0 + w1/x1 + w2/x2 + w3/x3,
// x_j = fma(s_j, v_j, 1). 13 VALU + 1 rcp per 4 elements. (Proven R3+.)
__device__ __forceinline__ float g4(float s0, float s1, float s2, float s3,
                                    float w0, float w1, float w2, float w3,
                                    float4 v, float acc) {
  float x0 = fmaf(s0, v.x, 1.f);
  float x1 = fmaf(s1, v.y, 1.f);
  float x2 = fmaf(s2, v.z, 1.f);
  float x3 = fmaf(s3, v.w, 1.f);
  float p01 = x0 * x1, p23 = x2 * x3;
  float n01 = fmaf(w1, x0, w0 * x1);
  float n23 = fmaf(w3, x2, w2 * x3);
  float num = fmaf(n23, p01, n01 * p23);
  return fmaf(num, frcp(p01 * p23), acc);
}

// Fused projections (UNCHANGED from R10). Blocks [0,nbTP): etp[n][h] natural
// layout. Blocks [nbTP,..): esp4 PACKED [h/4][b][4]; plus C = sum(W3)+b3.
__global__ __launch_bounds__(256) void taa_k1(
    const float* __restrict__ sess, const float* __restrict__ W1,
    const float* __restrict__ b1, const float* __restrict__ emb,
    const float* __restrict__ W2, const float* __restrict__ b2,
    const float* __restrict__ W3, const float* __restrict__ b3,
    float* __restrict__ etp, float* __restrict__ esp4,
    float* __restrict__ C_out, int N, int nbTP) {
  if ((int)blockIdx.x < nbTP) {
    __shared__ float sm[32][132];  // emb tile, padded stride
    const int nb = blockIdx.x * 32;
    for (int k = threadIdx.x; k < 32 * 32; k += 256) {
      int r = k >> 5, c4 = k & 31;
      float4 v = make_float4(0.f, 0.f, 0.f, 0.f);
      if (nb + r < N) v = ((const float4*)(emb + (size_t)(nb + r) * EDIM))[c4];
      *(float4*)&sm[r][c4 * 4] = v;
    }
    __syncthreads();
    const int h4 = (threadIdx.x & 31) * 4;
    const int rg = threadIdx.x >> 5;  // 8 groups of 4 rows
    float acc[4][4];
#pragma unroll
    for (int j = 0; j < 4; ++j)
#pragma unroll
      for (int q = 0; q < 4; ++q) acc[j][q] = 0.f;
    for (int e = 0; e < EDIM; e += 4) {
      float4 w[4];
#pragma unroll
      for (int q = 0; q < 4; ++q)
        w[q] = *(const float4*)(W2 + (size_t)(e + q) * HDIM + h4);
#pragma unroll
      for (int j = 0; j < 4; ++j) {
        float4 em = *(const float4*)&sm[rg * 4 + j][e];
        acc[j][0] = fmaf(em.x, w[0].x, acc[j][0]);
        acc[j][1] = fmaf(em.x, w[0].y, acc[j][1]);
        acc[j][2] = fmaf(em.x, w[0].z, acc[j][2]);
        acc[j][3] = fmaf(em.x, w[0].w, acc[j][3]);
        acc[j][0] = fmaf(em.y, w[1].x, acc[j][0]);
        acc[j][1] = fmaf(em.y, w[1].y, acc[j][1]);
        acc[j][2] = fmaf(em.y, w[1].z, acc[j][2]);
        acc[j][3] = fmaf(em.y, w[1].w, acc[j][3]);
        acc[j][0] = fmaf(em.z, w[2].x, acc[j][0]);
        acc[j][1] = fmaf(em.z, w[2].y, acc[j][1]);
        acc[j][2] = fmaf(em.z, w[2].z, acc[j][2]);
        acc[j][3] = fmaf(em.z, w[2].w, acc[j][3]);
        acc[j][0] = fmaf(em.w, w[3].x, acc[j][0]);
        acc[j][1] = fmaf(em.w, w[3].y, acc[j][1]);
        acc[j][2] = fmaf(em.w, w[3].z, acc[j][2]);
        acc[j][3] = fmaf(em.w, w[3].w, acc[j][3]);
      }
    }
    float4 bb2 = *(const float4*)(b2 + h4);
#pragma unroll
    for (int j = 0; j < 4; ++j) {
      int n = nb + rg * 4 + j;
      if (n < N) {
        float4 o;
        o.x = fexp2((acc[j][0] + bb2.x) * KSCALE);
        o.y = fexp2((acc[j][1] + bb2.y) * KSCALE);
        o.z = fexp2((acc[j][2] + bb2.z) * KSCALE);
        o.w = fexp2((acc[j][3] + bb2.w) * KSCALE);
        *(float4*)(etp + (size_t)n * HDIM + h4) = o;
      }
    }
  } else {
    int t = ((int)blockIdx.x - nbTP) * 256 + threadIdx.x;
    if (t < BSES * HDIM) {
      int b = t >> 7, h = t & 127;
      const float* srow = sess + b * EDIM;
      float acc = 0.f;
#pragma unroll 4
      for (int e = 0; e < EDIM; ++e)
        acc = fmaf(srow[e], W1[e * HDIM + h], acc);
      esp4[(h >> 2) * 256 + b * 4 + (h & 3)] = fexp2((acc + b1[h]) * KSCALE);
    }
    if (t == 0) {
      float s = b3[0];
      for (int i = 0; i < HDIM; ++i) s += W3[i];
      *C_out = s;
    }
  }
}

// Score 4 targets (rows t0..t0+3 of an LDS half) for this lane's session.
// Target values: uniform LDS broadcasts (free). sp: L1-hot coalesced
// dwordx4, amortized over 4 targets. w3: uniform -> s_load.
__device__ __forceinline__ void score_half(
    const float* __restrict__ eth,  // LDS half base (16 rows x 132)
    int t0, int lane, const float* __restrict__ esp4,
    const float* __restrict__ w3, float acc[4]) {
  const float* base = eth + t0 * 132;
#pragma unroll 2
  for (int c = 0; c < 8; ++c) {
    float4 sp[4];
#pragma unroll
    for (int k = 0; k < 4; ++k)
      sp[k] = *(const float4*)(esp4 + ((c << 2) + k) * 256 + (lane << 2));
    float w_[16];
#pragma unroll
    for (int k = 0; k < 16; ++k) w_[k] = w3[(c << 4) + k];
#pragma unroll
    for (int t = 0; t < 4; ++t) {
      const float* rp = base + t * 132 + (c << 4);
      float4 v0 = *(const float4*)(rp + 0);   // ds_read_b128 broadcast
      float4 v1 = *(const float4*)(rp + 4);
      float4 v2 = *(const float4*)(rp + 8);
      float4 v3 = *(const float4*)(rp + 12);
      acc[t] = g4(sp[0].x, sp[0].y, sp[0].z, sp[0].w,
                  w_[0], w_[1], w_[2], w_[3], v0, acc[t]);
      acc[t] = g4(sp[1].x, sp[1].y, sp[1].z, sp[1].w,
                  w_[4], w_[5], w_[6], w_[7], v1, acc[t]);
      acc[t] = g4(sp[2].x, sp[2].y, sp[2].z, sp[2].w,
                  w_[8], w_[9], w_[10], w_[11], v2, acc[t]);
      acc[t] = g4(sp[3].x, sp[3].y, sp[3].z, sp[3].w,
                  w_[12], w_[13], w_[14], w_[15], v3, acc[t]);
    }
  }
}

// Scoring: block = 32-target tile staged into LDS in two 16-row halves.
// Staging = 512 independent coalesced dwordx4 in flight per half (block-
// level latency amortization); half-1 loads issue BEFORE half-0 compute
// (T14 async-stage split). Scoring reads: LDS broadcast (targets) + L1
// coalesced (sp). lane = session; wave w scores rows w*4..+3 of each half.
// score[b][n] = C - 2 * sum_h w3[h] * rcp(fma(esp[b][h], etp[n][h], 1))
__global__ __launch_bounds__(256) void taa_k2(
    const float* __restrict__ etp, const float* __restrict__ esp4,
    const float* __restrict__ w3, const float* __restrict__ Cptr,
    float* __restrict__ out, int N) {
  __shared__ float et[2][16 * 132];
  const int tid = threadIdx.x;
  const int lane = tid & 63;
  const int wv = tid >> 6;  // 0..3
  const int nb = blockIdx.x * 32;

  // Stage half 0 (rows nb..nb+15): thread -> rows r0 and r0+8, 16B each.
  const int r0 = tid >> 5, c4 = tid & 31;
  const float* src0 = etp + (size_t)(nb + r0) * HDIM + c4 * 4;
  float4 a0 = *(const float4*)src0;
  float4 a1 = *(const float4*)(src0 + 8 * HDIM);
  *(float4*)&et[0][r0 * 132 + c4 * 4] = a0;
  *(float4*)&et[0][(r0 + 8) * 132 + c4 * 4] = a1;
  __syncthreads();

  // Issue half-1 loads EARLY (latency hides under half-0 scoring).
  const float* src1 = src0 + 16 * HDIM;
  float4 b0 = *(const float4*)src1;
  float4 b1 = *(const float4*)(src1 + 8 * HDIM);

  float acc0[4] = {0.f, 0.f, 0.f, 0.f};
  score_half(et[0], wv * 4, lane, esp4, w3, acc0);

  // Write half 1 (no WAR on et[0]; barrier only before reading et[1]).
  *(float4*)&et[1][r0 * 132 + c4 * 4] = b0;
  *(float4*)&et[1][(r0 + 8) * 132 + c4 * 4] = b1;
  __syncthreads();

  float acc1[4] = {0.f, 0.f, 0.f, 0.f};
  score_half(et[1], wv * 4, lane, esp4, w3, acc1);

  const float Cv = *Cptr;  // uniform -> s_load
  const int n0 = nb + wv * 4;       // half-0 targets (contiguous 4)
  const int n1 = n0 + 16;           // half-1 targets
  float4 res0, res1;
  res0.x = fmaf(-2.f, acc0[0], Cv);
  res0.y = fmaf(-2.f, acc0[1], Cv);
  res0.z = fmaf(-2.f, acc0[2], Cv);
  res0.w = fmaf(-2.f, acc0[3], Cv);
  res1.x = fmaf(-2.f, acc1[0], Cv);
  res1.y = fmaf(-2.f, acc1[1], Cv);
  res1.z = fmaf(-2.f, acc1[2], Cv);
  res1.w = fmaf(-2.f, acc1[3], Cv);
  float* po = out + (size_t)lane * N;
  if (n0 + 3 < N) {
    *(float4*)(po + n0) = res0;
  } else {
    float r4[4] = {res0.x, res0.y, res0.z, res0.w};
    for (int i = 0; i < 4 && n0 + i < N; ++i) po[n0 + i] = r4[i];
  }
  if (n1 + 3 < N) {
    *(float4*)(po + n1) = res1;
  } else {
    float r4[4] = {res1.x, res1.y, res1.z, res1.w};
    for (int i = 0; i < 4 && n1 + i < N; ++i) po[n1 + i] = r4[i];
  }
}

extern "C" void kernel_launch(void* const* d_in, const int* in_sizes, int n_in,
                              void* d_out, int out_size, void* d_ws, size_t ws_size,
                              hipStream_t stream) {
  const float* sess = (const float*)d_in[0];
  const float* emb  = (const float*)d_in[1];
  const float* W1   = (const float*)d_in[2];
  const float* b1   = (const float*)d_in[3];
  const float* W2   = (const float*)d_in[4];
  const float* b2   = (const float*)d_in[5];
  const float* W3   = (const float*)d_in[6];
  const float* b3   = (const float*)d_in[7];
  float* out = (float*)d_out;
  const int B = in_sizes[0] / EDIM;   // 64
  const int N = in_sizes[1] / EDIM;   // 20000

  float* etp  = (float*)d_ws;                     // N*128 floats
  float* esp4 = etp + (size_t)N * HDIM;           // B*128 floats (packed)
  float* Cp   = esp4 + (size_t)BSES * HDIM;       // 1 float

  const int nbTP = (N + 31) / 32;                 // 625
  const int nbSP = (B * HDIM + 255) / 256;        // 32
  taa_k1<<<nbTP + nbSP, 256, 0, stream>>>(sess, W1, b1, emb, W2, b2, W3, b3,
                                          etp, esp4, Cp, N, nbTP);
  taa_k2<<<(N + 31) / 32, 256, 0, stream>>>(etp, esp4, W3, Cp, out, N);
}